// Round 10
// baseline (290.548 us; speedup 1.0000x reference)
//
#include <hip/hip_runtime.h>
#include <math.h>

// Problem constants
constexpr int Bb = 2, Ss = 2048, Dd = 1024, Hh = 16, Kk = 16;
constexpr float DELTA = 0.02f;   // candidate margin (~30 sigma of bf16 approx error)

typedef __bf16 bf16x8 __attribute__((ext_vector_type(8)));
typedef __bf16 bf16x4 __attribute__((ext_vector_type(4)));
typedef float  f32x4  __attribute__((ext_vector_type(4)));

__device__ __forceinline__ void gld_lds16(const void* g, void* l) {
    __builtin_amdgcn_global_load_lds(
        (const __attribute__((address_space(1))) unsigned int*)g,
        (__attribute__((address_space(3))) unsigned int*)l, 16, 0, 0);
}

// ---------------------------------------------------------------------------
// FUSED GEMM dispatch: uniform bf16 MFMA GEMM, 256x128 tile, BK=32, 512
// threads / 8 waves (each a 64x64 quadrant; 4 m-quadrants x 2 n-halves).
// 28 column-blocks per row-tile: cb 0..23 QKV (bias + bf16 store); cb 24..27
// approximate indexer (relu*Ws2 row-reduce -> atomicAdd imp; exact rescore
// of a candidate band follows, so approx here is selection-safe).
// 256-row tiles cut L2->LDS staging traffic 2.7x vs 128-row (918->344 MB).
// Linear (non-swizzled) LDS layout: swizzle measured neutral-to-negative.
// Grid 448 = 16 row-tiles x 28.
// ---------------------------------------------------------------------------
__global__ void __launch_bounds__(512) gemm_qkv_ind(
    const __bf16* __restrict__ xb, const __bf16* __restrict__ WqkvT,
    const __bf16* __restrict__ W1Th,
    const float* __restrict__ bq, const float* __restrict__ bk,
    const float* __restrict__ bv,
    __bf16* __restrict__ qb, __bf16* __restrict__ kb, __bf16* __restrict__ vb,
    const float* __restrict__ bs1, const float* __restrict__ Ws2,
    float* __restrict__ imp)
{
    __shared__ __bf16 As[256 * 32];   // 16 KB
    __shared__ __bf16 Bs[128 * 32];   // 8 KB

    const int bid  = blockIdx.x;
    const int cb   = bid % 28;
    const int bm   = (bid / 28) * 256;
    const int t    = threadIdx.x;
    const int wave = t >> 6;
    const int lane = t & 63;
    const int fr   = lane & 15;
    const int fq   = lane >> 4;
    const int K    = Dd;
    const bool ind = (cb >= 24);

    const __bf16* BT = ind ? (W1Th + (size_t)(cb - 24) * 128 * 1024)
                           : (WqkvT + (size_t)cb * 128 * 1024);

    const int wm = (wave & 3) * 64;
    const int wn = (wave >> 2) * 64;

    f32x4 acc[4][4] = {};

    for (int k0 = 0; k0 < K; k0 += 32) {
        // A: 256 rows x 32 k = 1024 chunks of 16 B; 2 per thread.
        #pragma unroll
        for (int l = 0; l < 2; ++l) {
            int c = l * 512 + t;
            int row = c >> 2, seg = c & 3;
            gld_lds16(xb + (size_t)(bm + row) * K + k0 + seg * 8,
                      As + (size_t)(l * 512 + wave * 64) * 8);
        }
        // B: 128 rows x 32 k = 512 chunks; 1 per thread.
        {
            int row = t >> 2, seg = t & 3;
            gld_lds16(BT + (size_t)row * K + k0 + seg * 8,
                      Bs + (size_t)(wave * 64) * 8);
        }
        __syncthreads();

        bf16x8 af[4], bf[4];
        #pragma unroll
        for (int i = 0; i < 4; ++i)
            af[i] = *(const bf16x8*)(As + (wm + i * 16 + fr) * 32 + fq * 8);
        #pragma unroll
        for (int j = 0; j < 4; ++j)
            bf[j] = *(const bf16x8*)(Bs + (wn + j * 16 + fr) * 32 + fq * 8);
        #pragma unroll
        for (int i = 0; i < 4; ++i)
            #pragma unroll
            for (int j = 0; j < 4; ++j)
                acc[i][j] = __builtin_amdgcn_mfma_f32_16x16x32_bf16(af[i], bf[j], acc[i][j], 0, 0, 0);
        __syncthreads();
    }

    const int cr = (lane >> 4) * 4;
    const int cc = lane & 15;

    if (!ind) {
        const int zone = cb >> 3;                       // 0=q 1=k 2=v
        const int cl0  = cb * 128 - zone * 1024;
        const float* bias = (zone == 0) ? bq : (zone == 1) ? bk : bv;
        __bf16*      C    = (zone == 0) ? qb : (zone == 1) ? kb : vb;
        #pragma unroll
        for (int j = 0; j < 4; ++j) {
            int col = cl0 + wn + j * 16 + cc;
            float bb = bias[col];
            #pragma unroll
            for (int i = 0; i < 4; ++i) {
                #pragma unroll
                for (int r = 0; r < 4; ++r)
                    C[(size_t)(bm + wm + i * 16 + cr + r) * Dd + col] =
                        (__bf16)(acc[i][j][r] + bb);
            }
        }
    } else {
        const int hc0 = (cb - 24) * 128;
        float bb[4], w2[4];
        #pragma unroll
        for (int j = 0; j < 4; ++j) {
            int col = hc0 + wn + j * 16 + cc;
            bb[j] = bs1[col];
            w2[j] = Ws2[col];
        }
        #pragma unroll
        for (int i = 0; i < 4; ++i) {
            #pragma unroll
            for (int r = 0; r < 4; ++r) {
                float vsum = 0.f;
                #pragma unroll
                for (int j = 0; j < 4; ++j)
                    vsum += fmaxf(acc[i][j][r] + bb[j], 0.f) * w2[j];
                #pragma unroll
                for (int off = 8; off > 0; off >>= 1)
                    vsum += __shfl_xor(vsum, off, 16);
                if (cc == 0)
                    atomicAdd(imp + (bm + wm + i * 16 + cr + r), vsum);
            }
        }
    }
}

// ---------------------------------------------------------------------------
// Out-projection GEMM: out = att @ WoT^T + bo, f32 out. 64x128 tile, BK=64.
// ---------------------------------------------------------------------------
__global__ void __launch_bounds__(256) gemm_out(
    const __bf16* __restrict__ A, const __bf16* __restrict__ BT,
    const float* __restrict__ bias, float* __restrict__ C, int M, int N, int K)
{
    __shared__ __bf16 As[64 * 64];
    __shared__ __bf16 Bs[128 * 64];

    const int t    = threadIdx.x;
    const int wave = t >> 6;
    const int lane = t & 63;
    const int bm   = blockIdx.y * 64;
    const int bn   = blockIdx.x * 128;
    const int wm   = (wave & 1) * 32;
    const int wn   = (wave >> 1) * 64;
    const int fr   = lane & 15;
    const int fq   = lane >> 4;

    f32x4 acc[2][4] = {};

    for (int k0 = 0; k0 < K; k0 += 64) {
        #pragma unroll
        for (int l = 0; l < 2; ++l) {
            int c = l * 256 + t;
            int row = c >> 3, seg = (c & 7) ^ (row & 7);
            gld_lds16(A + (size_t)(bm + row) * K + k0 + seg * 8,
                      As + (size_t)(l * 256 + wave * 64) * 8);
        }
        #pragma unroll
        for (int l = 0; l < 4; ++l) {
            int c = l * 256 + t;
            int row = c >> 3, seg = (c & 7) ^ (row & 7);
            gld_lds16(BT + (size_t)(bn + row) * K + k0 + seg * 8,
                      Bs + (size_t)(l * 256 + wave * 64) * 8);
        }
        __syncthreads();

        #pragma unroll
        for (int s = 0; s < 2; ++s) {
            bf16x8 af[2], bf[4];
            #pragma unroll
            for (int i = 0; i < 2; ++i) {
                int row = wm + i * 16 + fr;
                af[i] = *(const bf16x8*)(As + row * 64 + (((s * 4 + fq) ^ (row & 7)) * 8));
            }
            #pragma unroll
            for (int j = 0; j < 4; ++j) {
                int row = wn + j * 16 + fr;
                bf[j] = *(const bf16x8*)(Bs + row * 64 + (((s * 4 + fq) ^ (row & 7)) * 8));
            }
            #pragma unroll
            for (int i = 0; i < 2; ++i)
                #pragma unroll
                for (int j = 0; j < 4; ++j)
                    acc[i][j] = __builtin_amdgcn_mfma_f32_16x16x32_bf16(af[i], bf[j], acc[i][j], 0, 0, 0);
        }
        __syncthreads();
    }

    const int cr = (lane >> 4) * 4;
    const int cc = lane & 15;
    #pragma unroll
    for (int j = 0; j < 4; ++j) {
        int col = bn + wn + j * 16 + cc;
        float bb = bias[col];
        #pragma unroll
        for (int i = 0; i < 2; ++i) {
            #pragma unroll
            for (int r = 0; r < 4; ++r)
                C[(size_t)(bm + wm + i * 16 + cr + r) * N + col] = acc[i][j][r] + bb;
        }
    }
}

// ---------------------------------------------------------------------------
// Merged prep: bid<4096 -> pack x (f32 -> bf16) + zero-init imp/oacc/lsum/
// hbuf/ccount; bid>=4096 -> weight transpose+pack.
// ---------------------------------------------------------------------------
__global__ void __launch_bounds__(256) prep_kernel(
    const float* __restrict__ x, __bf16* __restrict__ xb,
    float* __restrict__ imp, float* __restrict__ oacc,
    float* __restrict__ lsum, float* __restrict__ hbuf,
    int* __restrict__ ccount,
    const float* __restrict__ W0, const float* __restrict__ W1,
    const float* __restrict__ W2, const float* __restrict__ W3,
    __bf16* __restrict__ WqkvT, __bf16* __restrict__ WoT,
    const float* __restrict__ Ws1, __bf16* __restrict__ Th)
{
    __shared__ float tile[32][33];
    const int bid = blockIdx.x;

    if (bid < 4096) {
        int i = bid * 256 + threadIdx.x;
        if (i < Bb * Ss) imp[i] = 0.f;
        if (i < Bb * Hh * Kk * 64) oacc[i] = 0.f;
        if (i < Bb * Hh * Kk) lsum[i] = 0.f;
        if (i < Bb * 64 * 512) hbuf[i] = 0.f;
        if (i < Bb) ccount[i] = 0;
        float4 v = ((const float4*)x)[i];
        bf16x4 h = { (__bf16)v.x, (__bf16)v.y, (__bf16)v.z, (__bf16)v.w };
        ((bf16x4*)xb)[i] = h;
        return;
    }

    int tid = bid - 4096;
    int z   = tid >> 10;
    int rem = tid & 1023;
    int n0  = (rem & 31) * 32;
    int k0  = (rem >> 5) * 32;
    int tx = threadIdx.x & 31, ty = threadIdx.x >> 5;

    if (z < 4) {
        const float* W = (z == 0) ? W0 : (z == 1) ? W1 : (z == 2) ? W2 : W3;
        __bf16*      T = (z < 3) ? (WqkvT + (size_t)z * 1024 * 1024) : WoT;
        #pragma unroll
        for (int i = 0; i < 32; i += 8)
            tile[ty + i][tx] = W[(size_t)(k0 + ty + i) * 1024 + n0 + tx];
        __syncthreads();
        #pragma unroll
        for (int i = 0; i < 32; i += 8)
            T[(size_t)(n0 + ty + i) * 1024 + k0 + tx] = (__bf16)tile[tx][ty + i];
    } else {
        if (n0 >= 512) return;
        #pragma unroll
        for (int i = 0; i < 32; i += 8)
            tile[ty + i][tx] = Ws1[(size_t)(k0 + ty + i) * 512 + n0 + tx];
        __syncthreads();
        #pragma unroll
        for (int i = 0; i < 32; i += 8)
            Th[(size_t)(n0 + ty + i) * 1024 + k0 + tx] = (__bf16)tile[tx][ty + i];
    }
}

// ---------------------------------------------------------------------------
// Candidate generation on approx imp: 16 argmax passes at 1024 threads
// (2 elems/thread/pass) + threshold band z16_approx - DELTA. Cap 64.
// ---------------------------------------------------------------------------
__global__ void __launch_bounds__(1024) topk_cand(
    const float* __restrict__ imp, int* __restrict__ cand_idx,
    int* __restrict__ ccount)
{
    int b = blockIdx.x;
    int t = threadIdx.x;
    int wave = t >> 6, lane = t & 63;   // 16 waves
    __shared__ float vals[Ss];
    __shared__ float sv[16];
    __shared__ int   si[16];
    __shared__ float thr_s;
    __shared__ int   cnt_s;

    vals[t]        = imp[b * Ss + t];
    vals[t + 1024] = imp[b * Ss + t + 1024];
    __syncthreads();

    for (int it = 0; it < Kk; ++it) {
        float v0 = vals[t], v1 = vals[t + 1024];
        float best = v0; int bidx = t;
        if (v1 > best) { best = v1; bidx = t + 1024; }
        #pragma unroll
        for (int off = 32; off > 0; off >>= 1) {
            float ov = __shfl_xor(best, off, 64);
            int   oi = __shfl_xor(bidx, off, 64);
            if (ov > best || (ov == best && oi < bidx)) { best = ov; bidx = oi; }
        }
        if (lane == 0) { sv[wave] = best; si[wave] = bidx; }
        __syncthreads();
        if (t == 0) {
            float bv = sv[0]; int br = si[0];
            #pragma unroll
            for (int w = 1; w < 16; ++w)
                if (sv[w] > bv || (sv[w] == bv && si[w] < br)) { bv = sv[w]; br = si[w]; }
            cand_idx[b * 64 + it] = br;
            vals[br] = -1e30f;
            if (it == Kk - 1) { thr_s = bv - DELTA; cnt_s = Kk; }
        }
        __syncthreads();
    }

    float thr = thr_s;
    if (vals[t] > thr) {
        int p = atomicAdd(&cnt_s, 1);
        if (p < 64) cand_idx[b * 64 + p] = t;
    }
    if (vals[t + 1024] > thr) {
        int p = atomicAdd(&cnt_s, 1);
        if (p < 64) cand_idx[b * 64 + p] = t + 1024;
    }
    __syncthreads();
    if (t == 0) ccount[b] = min(cnt_s, 64);
}

// ---------------------------------------------------------------------------
// Exact f32 rescore, phase 1: partial h for candidate rows, K split into 16
// chunks of 64 (grid 64 x 16 x Bb). relu deferred; atomic reorder ~1e-6.
// ---------------------------------------------------------------------------
__global__ void __launch_bounds__(256) rescore_h(
    const float* __restrict__ x, const float* __restrict__ Ws1,
    const int* __restrict__ cand_idx, const int* __restrict__ ccount,
    float* __restrict__ hbuf)
{
    const int c = blockIdx.x, kc = blockIdx.y, b = blockIdx.z;
    if (c >= ccount[b]) return;
    const int row = cand_idx[b * 64 + c];
    const int t = threadIdx.x;
    const int k0 = kc * 64;

    __shared__ float xs[64];
    if (t < 16)
        ((float4*)xs)[t] = ((const float4*)(x + ((size_t)(b * Ss + row)) * Dd + k0))[t];
    __syncthreads();

    float a0 = 0.f, a1 = 0.f;
    const float* W = Ws1 + (size_t)k0 * 512;
    #pragma unroll 16
    for (int kk = 0; kk < 64; ++kk) {
        float xv = xs[kk];
        a0 = fmaf(xv, W[kk * 512 + t], a0);
        a1 = fmaf(xv, W[kk * 512 + t + 256], a1);
    }
    float* hb = hbuf + ((size_t)(b * 64 + c)) * 512;
    atomicAdd(hb + t, a0);
    atomicAdd(hb + t + 256, a1);
}

// ---------------------------------------------------------------------------
// FUSED rescore finalize + exact top-16 select. One block per batch.
// z_c = sum relu(h_c + bs1) * Ws2 (pre-sigmoid; monotone => same ranking as
// reference f32 path). Then 16 butterfly-argmax passes among candidates
// (tie -> smaller row index, matching jax.lax.top_k stable order).
// ---------------------------------------------------------------------------
__global__ void __launch_bounds__(256) rescore_sel(
    const float* __restrict__ hbuf, const float* __restrict__ bs1,
    const float* __restrict__ Ws2, const int* __restrict__ cand_idx,
    const int* __restrict__ ccount, int* __restrict__ sel_idx)
{
    const int b = blockIdx.x, t = threadIdx.x;
    const int wave = t >> 6, lane = t & 63;
    __shared__ float zv[64];
    __shared__ float sv[4];
    const int cnt = ccount[b];

    const float b0 = bs1[t],       b1 = bs1[t + 256];
    const float w0 = Ws2[t],       w1 = Ws2[t + 256];

    for (int c = 0; c < cnt; ++c) {
        const float* hb = hbuf + ((size_t)(b * 64 + c)) * 512;
        float zp = fmaxf(hb[t] + b0, 0.f) * w0
                 + fmaxf(hb[t + 256] + b1, 0.f) * w1;
        #pragma unroll
        for (int off = 32; off > 0; off >>= 1) zp += __shfl_xor(zp, off, 64);
        if (lane == 0) sv[wave] = zp;
        __syncthreads();
        if (t == 0) zv[c] = (sv[0] + sv[1]) + (sv[2] + sv[3]);
        __syncthreads();
    }

    if (t < 64) {
        float val = (t < cnt) ? zv[t] : -1e30f;
        int   row = (t < cnt) ? cand_idx[b * 64 + t] : 0x7fffffff;
        for (int it = 0; it < Kk; ++it) {
            float bv = val; int br = row;
            #pragma unroll
            for (int off = 1; off < 64; off <<= 1) {
                float ov = __shfl_xor(bv, off, 64);
                int   orw = __shfl_xor(br, off, 64);
                if (ov > bv || (ov == bv && orw < br)) { bv = ov; br = orw; }
            }
            if (row == br) val = -1e30f;
            if (t == 0) sel_idx[b * Kk + it] = br;
        }
    }
}

// ---------------------------------------------------------------------------
// Sparse attention: ALL rows attend over the 16 selected keys (selected rows
// overwritten by the dense pipeline). One block per (b, h, 16 queries).
// ---------------------------------------------------------------------------
__global__ void __launch_bounds__(256) attn_sparse(
    const __bf16* __restrict__ q, const __bf16* __restrict__ k,
    const __bf16* __restrict__ v, const int* __restrict__ sel_idx,
    __bf16* __restrict__ att)
{
    const int b  = blockIdx.z;
    const int h  = blockIdx.y;
    const int q0 = blockIdx.x * 16;
    const int t  = threadIdx.x;

    __shared__ float KT[64][17];
    __shared__ float Vs[16][64];
    __shared__ float qsh[16][65];
    __shared__ float wsh[16][16];
    __shared__ int   sj[16];

    if (t < 16) sj[t] = sel_idx[b * Kk + t];
    __syncthreads();

    {
        int row = t >> 4, d0 = (t & 15) * 4;
        bf16x4 kv = *(const bf16x4*)(k + ((size_t)(b * Ss + sj[row])) * Dd + h * 64 + d0);
        bf16x4 vv = *(const bf16x4*)(v + ((size_t)(b * Ss + sj[row])) * Dd + h * 64 + d0);
        bf16x4 qv = *(const bf16x4*)(q + ((size_t)(b * Ss + q0 + row)) * Dd + h * 64 + d0);
        #pragma unroll
        for (int i = 0; i < 4; ++i) {
            KT[d0 + i][row]  = (float)kv[i];
            Vs[row][d0 + i]  = (float)vv[i];
            qsh[row][d0 + i] = (float)qv[i];
        }
    }
    __syncthreads();

    const int wave = t >> 6, lane = t & 63;
    const int ql = lane >> 4, j = lane & 15;
    const int qi = wave * 4 + ql;

    float s = 0.f;
    #pragma unroll
    for (int d = 0; d < 64; ++d) s = fmaf(qsh[qi][d], KT[d][j], s);
    s *= 0.125f;

    float m = s;
    #pragma unroll
    for (int off = 8; off > 0; off >>= 1) m = fmaxf(m, __shfl_xor(m, off, 16));
    float e = __expf(s - m);
    float sum = e;
    #pragma unroll
    for (int off = 8; off > 0; off >>= 1) sum += __shfl_xor(sum, off, 16);
    wsh[qi][j] = e / sum;

    #pragma unroll
    for (int q2 = 0; q2 < 4; ++q2) {
        int qq = wave * 4 + q2;
        float o = 0.f;
        #pragma unroll
        for (int jj = 0; jj < 16; ++jj)
            o = fmaf(wsh[qq][jj], Vs[jj][lane], o);
        att[((size_t)(b * Ss + q0 + qq)) * Dd + h * 64 + lane] = (__bf16)o;
    }
}

// ---------------------------------------------------------------------------
// Merged dense attention: scores -> exp (no max subtraction; |s|<=~3 so f32
// exp is safe; softmax shift-invariant) -> lsum atomics -> PV -> oacc atomics.
// K-tile LDS reused for V after barrier. Grid (16 chunks, Hh, Bb).
// ---------------------------------------------------------------------------
__global__ void __launch_bounds__(256) attn_dense_one(
    const __bf16* __restrict__ q, const __bf16* __restrict__ k,
    const __bf16* __restrict__ v, const int* __restrict__ sel_idx,
    float* __restrict__ lsum, float* __restrict__ oacc)
{
    const int b  = blockIdx.z, h = blockIdx.y, j0 = blockIdx.x * 128;
    const int t  = threadIdx.x;

    __shared__ float Ks[128][65];    // reused for V in phase 2
    __shared__ float Qs[16][65];
    __shared__ float Es[16][144];

    #pragma unroll
    for (int l = 0; l < 4; ++l) {
        int c = t + 256 * l;
        int row = c >> 3, seg = c & 7;
        bf16x8 kv = *(const bf16x8*)(k + ((size_t)(b * Ss + j0 + row)) * Dd + h * 64 + seg * 8);
        #pragma unroll
        for (int e = 0; e < 8; ++e) Ks[row][seg * 8 + e] = (float)kv[e];
    }
    if (t < 128) {
        int row = t >> 3, seg = t & 7;
        int i = sel_idx[b * Kk + row];
        bf16x8 qv = *(const bf16x8*)(q + ((size_t)(b * Ss + i)) * Dd + h * 64 + seg * 8);
        #pragma unroll
        for (int e = 0; e < 8; ++e) Qs[row][seg * 8 + e] = (float)qv[e];
    }
    __syncthreads();

    const int qi = t >> 4, ks = t & 15;
    const int bhq = (b * Hh + h) * Kk + qi;
    float psum = 0.f;
    #pragma unroll
    for (int s8 = 0; s8 < 8; ++s8) {
        int j = ks + s8 * 16;
        float s = 0.f;
        #pragma unroll
        for (int d = 0; d < 64; ++d) s = fmaf(Qs[qi][d], Ks[j][d], s);
        float e = __expf(s * 0.125f);
        Es[qi][j] = e;
        psum += e;
    }
    #pragma unroll
    for (int off = 8; off > 0; off >>= 1) psum += __shfl_xor(psum, off, 16);
    if (ks == 0) atomicAdd(lsum + bhq, psum);
    __syncthreads();

    #pragma unroll
    for (int l = 0; l < 4; ++l) {
        int c = t + 256 * l;
        int row = c >> 3, seg = c & 7;
        bf16x8 vv = *(const bf16x8*)(v + ((size_t)(b * Ss + j0 + row)) * Dd + h * 64 + seg * 8);
        #pragma unroll
        for (int e = 0; e < 8; ++e) Ks[row][seg * 8 + e] = (float)vv[e];
    }
    __syncthreads();

    const int d = t & 63, qg = t >> 6;
    #pragma unroll
    for (int qq = 0; qq < 4; ++qq) {
        int qx = qg * 4 + qq;
        float o = 0.f;
        #pragma unroll 4
        for (int jj = 0; jj < 128; ++jj)
            o = fmaf(Es[qx][jj], Ks[jj][d], o);
        atomicAdd(oacc + (size_t)((b * Hh + h) * Kk + qx) * 64 + d, o);
    }
}

// ---------------------------------------------------------------------------
// Dense attention finalize: att[selected rows] = oacc / lsum.
// ---------------------------------------------------------------------------
__global__ void __launch_bounds__(64) attn_dense_fin(
    const float* __restrict__ oacc, const float* __restrict__ lsum,
    const int* __restrict__ sel_idx, __bf16* __restrict__ att)
{
    int bid = blockIdx.x;
    int qi = bid & 15, h = (bid >> 4) & 15, b = bid >> 8;
    int bhq = (b * Hh + h) * Kk + qi;
    int i = sel_idx[b * Kk + qi];
    float val = oacc[(size_t)bhq * 64 + threadIdx.x] / lsum[bhq];
    att[((size_t)(b * Ss + i)) * Dd + h * 64 + threadIdx.x] = (__bf16)val;
}

// ---------------------------------------------------------------------------
extern "C" void kernel_launch(void* const* d_in, const int* in_sizes, int n_in,
                              void* d_out, int out_size, void* d_ws, size_t ws_size,
                              hipStream_t stream)
{
    const float* x   = (const float*)d_in[0];
    const float* Wq  = (const float*)d_in[1];
    const float* bq  = (const float*)d_in[2];
    const float* Wk  = (const float*)d_in[3];
    const float* bk  = (const float*)d_in[4];
    const float* Wv  = (const float*)d_in[5];
    const float* bv  = (const float*)d_in[6];
    const float* Wo  = (const float*)d_in[7];
    const float* bo  = (const float*)d_in[8];
    const float* Ws1 = (const float*)d_in[9];
    const float* bs1 = (const float*)d_in[10];
    const float* Ws2 = (const float*)d_in[11];
    float* out = (float*)d_out;

    const size_t MSD = (size_t)Bb * Ss * Dd;   // 4,194,304
    const int M = Bb * Ss;                     // 4096

    char* p = (char*)d_ws;
    __bf16* qb  = (__bf16*)p; p += MSD * sizeof(__bf16);
    __bf16* kb  = (__bf16*)p; p += MSD * sizeof(__bf16);
    __bf16* vb  = (__bf16*)p; p += MSD * sizeof(__bf16);
    __bf16* att = (__bf16*)p; p += MSD * sizeof(__bf16);
    __bf16* xb  = (__bf16*)p; p += MSD * sizeof(__bf16);
    __bf16* WqkvT = (__bf16*)p; p += (size_t)3 * Dd * Dd * sizeof(__bf16);
    __bf16* WoT   = (__bf16*)p; p += (size_t)Dd * Dd * sizeof(__bf16);
    __bf16* W1Th  = (__bf16*)p; p += (size_t)512 * Dd * sizeof(__bf16);
    float* imp  = (float*)p; p += (size_t)Bb * Ss * sizeof(float);
    int* sel_idx = (int*)p; p += (size_t)Bb * Kk * sizeof(int);
    float* oacc = (float*)p; p += (size_t)Bb * Hh * Kk * 64 * sizeof(float);
    float* lsum = (float*)p; p += (size_t)Bb * Hh * Kk * sizeof(float);
    float* hbuf = (float*)p; p += (size_t)Bb * 64 * 512 * sizeof(float);
    int* ccount   = (int*)p; p += Bb * sizeof(int);
    int* cand_idx = (int*)p; p += (size_t)Bb * 64 * sizeof(int);

    // 1) Merged prep: pack x -> bf16 (+ zero accumulators), weight transposes.
    prep_kernel<<<dim3(4096 + 5120), 256, 0, stream>>>(
        x, xb, imp, oacc, lsum, hbuf, ccount,
        Wq, Wk, Wv, Wo, WqkvT, WoT, Ws1, W1Th);
    // 2) FUSED: QKV projections + approximate indexer (256x128 tiles).
    gemm_qkv_ind<<<dim3(448), 512, 0, stream>>>(
        xb, WqkvT, W1Th, bq, bk, bv, qb, kb, vb, bs1, Ws2, imp);
    // 3) Candidate generation (approx top-16 + threshold band), 1024 thr.
    topk_cand<<<dim3(Bb), 1024, 0, stream>>>(imp, cand_idx, ccount);
    // 4) Exact f32 rescore (k-split partial h), then fused finalize+select.
    rescore_h<<<dim3(64, 16, Bb), 256, 0, stream>>>(x, Ws1, cand_idx, ccount, hbuf);
    rescore_sel<<<dim3(Bb), 256, 0, stream>>>(hbuf, bs1, Ws2, cand_idx, ccount, sel_idx);
    // 5) Attention: sparse writes all rows; merged dense overwrites selected.
    attn_sparse<<<dim3(Ss / 16, Hh, Bb), 256, 0, stream>>>(qb, kb, vb, sel_idx, att);
    attn_dense_one<<<dim3(Ss / 128, Hh, Bb), 256, 0, stream>>>(qb, kb, vb, sel_idx, lsum, oacc);
    attn_dense_fin<<<dim3(Bb * Hh * Kk), 64, 0, stream>>>(oacc, lsum, sel_idx, att);
    // 6) Output projection: 64x128 tile, BK=64, 512 blocks.
    gemm_out<<<dim3(8, 64), 256, 0, stream>>>(att, WoT, bo, out, M, Dd, Dd);
}

// Round 11
// 252.569 us; speedup vs baseline: 1.1504x; 1.1504x over previous
//
#include <hip/hip_runtime.h>
#include <math.h>

// Problem constants
constexpr int Bb = 2, Ss = 2048, Dd = 1024, Hh = 16, Kk = 16;
constexpr float DELTA = 0.02f;   // candidate margin (~30 sigma of bf16 approx error)

typedef __bf16 bf16x8 __attribute__((ext_vector_type(8)));
typedef __bf16 bf16x4 __attribute__((ext_vector_type(4)));
typedef float  f32x4  __attribute__((ext_vector_type(4)));

__device__ __forceinline__ void gld_lds16(const void* g, void* l) {
    __builtin_amdgcn_global_load_lds(
        (const __attribute__((address_space(1))) unsigned int*)g,
        (__attribute__((address_space(3))) unsigned int*)l, 16, 0, 0);
}

// ---------------------------------------------------------------------------
// FUSED GEMM dispatch: uniform bf16 MFMA GEMM, 256x128 tile, BK=32, 512
// threads / 8 waves. cb 0..23 QKV (bias + bf16 store); cb 24..27 approximate
// indexer (relu*Ws2 row-reduce -> atomicAdd imp; exact rescore follows).
// Grid 448 = 16 row-tiles x 28.
// ---------------------------------------------------------------------------
__global__ void __launch_bounds__(512) gemm_qkv_ind(
    const __bf16* __restrict__ xb, const __bf16* __restrict__ WqkvT,
    const __bf16* __restrict__ W1Th,
    const float* __restrict__ bq, const float* __restrict__ bk,
    const float* __restrict__ bv,
    __bf16* __restrict__ qb, __bf16* __restrict__ kb, __bf16* __restrict__ vb,
    const float* __restrict__ bs1, const float* __restrict__ Ws2,
    float* __restrict__ imp)
{
    __shared__ __bf16 As[256 * 32];   // 16 KB
    __shared__ __bf16 Bs[128 * 32];   // 8 KB

    const int bid  = blockIdx.x;
    const int cb   = bid % 28;
    const int bm   = (bid / 28) * 256;
    const int t    = threadIdx.x;
    const int wave = t >> 6;
    const int lane = t & 63;
    const int fr   = lane & 15;
    const int fq   = lane >> 4;
    const int K    = Dd;
    const bool ind = (cb >= 24);

    const __bf16* BT = ind ? (W1Th + (size_t)(cb - 24) * 128 * 1024)
                           : (WqkvT + (size_t)cb * 128 * 1024);

    const int wm = (wave & 3) * 64;
    const int wn = (wave >> 2) * 64;

    f32x4 acc[4][4] = {};

    for (int k0 = 0; k0 < K; k0 += 32) {
        #pragma unroll
        for (int l = 0; l < 2; ++l) {
            int c = l * 512 + t;
            int row = c >> 2, seg = c & 3;
            gld_lds16(xb + (size_t)(bm + row) * K + k0 + seg * 8,
                      As + (size_t)(l * 512 + wave * 64) * 8);
        }
        {
            int row = t >> 2, seg = t & 3;
            gld_lds16(BT + (size_t)row * K + k0 + seg * 8,
                      Bs + (size_t)(wave * 64) * 8);
        }
        __syncthreads();

        bf16x8 af[4], bf[4];
        #pragma unroll
        for (int i = 0; i < 4; ++i)
            af[i] = *(const bf16x8*)(As + (wm + i * 16 + fr) * 32 + fq * 8);
        #pragma unroll
        for (int j = 0; j < 4; ++j)
            bf[j] = *(const bf16x8*)(Bs + (wn + j * 16 + fr) * 32 + fq * 8);
        #pragma unroll
        for (int i = 0; i < 4; ++i)
            #pragma unroll
            for (int j = 0; j < 4; ++j)
                acc[i][j] = __builtin_amdgcn_mfma_f32_16x16x32_bf16(af[i], bf[j], acc[i][j], 0, 0, 0);
        __syncthreads();
    }

    const int cr = (lane >> 4) * 4;
    const int cc = lane & 15;

    if (!ind) {
        const int zone = cb >> 3;                       // 0=q 1=k 2=v
        const int cl0  = cb * 128 - zone * 1024;
        const float* bias = (zone == 0) ? bq : (zone == 1) ? bk : bv;
        __bf16*      C    = (zone == 0) ? qb : (zone == 1) ? kb : vb;
        #pragma unroll
        for (int j = 0; j < 4; ++j) {
            int col = cl0 + wn + j * 16 + cc;
            float bb = bias[col];
            #pragma unroll
            for (int i = 0; i < 4; ++i) {
                #pragma unroll
                for (int r = 0; r < 4; ++r)
                    C[(size_t)(bm + wm + i * 16 + cr + r) * Dd + col] =
                        (__bf16)(acc[i][j][r] + bb);
            }
        }
    } else {
        const int hc0 = (cb - 24) * 128;
        float bb[4], w2[4];
        #pragma unroll
        for (int j = 0; j < 4; ++j) {
            int col = hc0 + wn + j * 16 + cc;
            bb[j] = bs1[col];
            w2[j] = Ws2[col];
        }
        #pragma unroll
        for (int i = 0; i < 4; ++i) {
            #pragma unroll
            for (int r = 0; r < 4; ++r) {
                float vsum = 0.f;
                #pragma unroll
                for (int j = 0; j < 4; ++j)
                    vsum += fmaxf(acc[i][j][r] + bb[j], 0.f) * w2[j];
                #pragma unroll
                for (int off = 8; off > 0; off >>= 1)
                    vsum += __shfl_xor(vsum, off, 16);
                if (cc == 0)
                    atomicAdd(imp + (bm + wm + i * 16 + cr + r), vsum);
            }
        }
    }
}

// ---------------------------------------------------------------------------
// Out-projection GEMM: out = att @ WoT^T + bo, f32 out. 64x128 tile, BK=64.
// ---------------------------------------------------------------------------
__global__ void __launch_bounds__(256) gemm_out(
    const __bf16* __restrict__ A, const __bf16* __restrict__ BT,
    const float* __restrict__ bias, float* __restrict__ C, int M, int N, int K)
{
    __shared__ __bf16 As[64 * 64];
    __shared__ __bf16 Bs[128 * 64];

    const int t    = threadIdx.x;
    const int wave = t >> 6;
    const int lane = t & 63;
    const int bm   = blockIdx.y * 64;
    const int bn   = blockIdx.x * 128;
    const int wm   = (wave & 1) * 32;
    const int wn   = (wave >> 1) * 64;
    const int fr   = lane & 15;
    const int fq   = lane >> 4;

    f32x4 acc[2][4] = {};

    for (int k0 = 0; k0 < K; k0 += 64) {
        #pragma unroll
        for (int l = 0; l < 2; ++l) {
            int c = l * 256 + t;
            int row = c >> 3, seg = (c & 7) ^ (row & 7);
            gld_lds16(A + (size_t)(bm + row) * K + k0 + seg * 8,
                      As + (size_t)(l * 256 + wave * 64) * 8);
        }
        #pragma unroll
        for (int l = 0; l < 4; ++l) {
            int c = l * 256 + t;
            int row = c >> 3, seg = (c & 7) ^ (row & 7);
            gld_lds16(BT + (size_t)(bn + row) * K + k0 + seg * 8,
                      Bs + (size_t)(l * 256 + wave * 64) * 8);
        }
        __syncthreads();

        #pragma unroll
        for (int s = 0; s < 2; ++s) {
            bf16x8 af[2], bf[4];
            #pragma unroll
            for (int i = 0; i < 2; ++i) {
                int row = wm + i * 16 + fr;
                af[i] = *(const bf16x8*)(As + row * 64 + (((s * 4 + fq) ^ (row & 7)) * 8));
            }
            #pragma unroll
            for (int j = 0; j < 4; ++j) {
                int row = wn + j * 16 + fr;
                bf[j] = *(const bf16x8*)(Bs + row * 64 + (((s * 4 + fq) ^ (row & 7)) * 8));
            }
            #pragma unroll
            for (int i = 0; i < 2; ++i)
                #pragma unroll
                for (int j = 0; j < 4; ++j)
                    acc[i][j] = __builtin_amdgcn_mfma_f32_16x16x32_bf16(af[i], bf[j], acc[i][j], 0, 0, 0);
        }
        __syncthreads();
    }

    const int cr = (lane >> 4) * 4;
    const int cc = lane & 15;
    #pragma unroll
    for (int j = 0; j < 4; ++j) {
        int col = bn + wn + j * 16 + cc;
        float bb = bias[col];
        #pragma unroll
        for (int i = 0; i < 2; ++i) {
            #pragma unroll
            for (int r = 0; r < 4; ++r)
                C[(size_t)(bm + wm + i * 16 + cr + r) * N + col] = acc[i][j][r] + bb;
        }
    }
}

// ---------------------------------------------------------------------------
// Merged prep: bid<4096 -> pack x (f32 -> bf16) + zero-init accumulators;
// bid>=4096 -> weight transpose+pack.
// ---------------------------------------------------------------------------
__global__ void __launch_bounds__(256) prep_kernel(
    const float* __restrict__ x, __bf16* __restrict__ xb,
    float* __restrict__ imp, float* __restrict__ oacc,
    float* __restrict__ lsum, float* __restrict__ hbuf,
    int* __restrict__ ccount,
    const float* __restrict__ W0, const float* __restrict__ W1,
    const float* __restrict__ W2, const float* __restrict__ W3,
    __bf16* __restrict__ WqkvT, __bf16* __restrict__ WoT,
    const float* __restrict__ Ws1, __bf16* __restrict__ Th)
{
    __shared__ float tile[32][33];
    const int bid = blockIdx.x;

    if (bid < 4096) {
        int i = bid * 256 + threadIdx.x;
        if (i < Bb * Ss) imp[i] = 0.f;
        if (i < Bb * Hh * Kk * 64) oacc[i] = 0.f;
        if (i < Bb * Hh * Kk) lsum[i] = 0.f;
        if (i < Bb * 64 * 512) hbuf[i] = 0.f;
        if (i < Bb) ccount[i] = 0;
        float4 v = ((const float4*)x)[i];
        bf16x4 h = { (__bf16)v.x, (__bf16)v.y, (__bf16)v.z, (__bf16)v.w };
        ((bf16x4*)xb)[i] = h;
        return;
    }

    int tid = bid - 4096;
    int z   = tid >> 10;
    int rem = tid & 1023;
    int n0  = (rem & 31) * 32;
    int k0  = (rem >> 5) * 32;
    int tx = threadIdx.x & 31, ty = threadIdx.x >> 5;

    if (z < 4) {
        const float* W = (z == 0) ? W0 : (z == 1) ? W1 : (z == 2) ? W2 : W3;
        __bf16*      T = (z < 3) ? (WqkvT + (size_t)z * 1024 * 1024) : WoT;
        #pragma unroll
        for (int i = 0; i < 32; i += 8)
            tile[ty + i][tx] = W[(size_t)(k0 + ty + i) * 1024 + n0 + tx];
        __syncthreads();
        #pragma unroll
        for (int i = 0; i < 32; i += 8)
            T[(size_t)(n0 + ty + i) * 1024 + k0 + tx] = (__bf16)tile[tx][ty + i];
    } else {
        if (n0 >= 512) return;
        #pragma unroll
        for (int i = 0; i < 32; i += 8)
            tile[ty + i][tx] = Ws1[(size_t)(k0 + ty + i) * 512 + n0 + tx];
        __syncthreads();
        #pragma unroll
        for (int i = 0; i < 32; i += 8)
            Th[(size_t)(n0 + ty + i) * 1024 + k0 + tx] = (__bf16)tile[tx][ty + i];
    }
}

// ---------------------------------------------------------------------------
// Candidate generation on approx imp: 16 argmax passes at 1024 threads
// + threshold band z16_approx - DELTA. Cap 64.
// ---------------------------------------------------------------------------
__global__ void __launch_bounds__(1024) topk_cand(
    const float* __restrict__ imp, int* __restrict__ cand_idx,
    int* __restrict__ ccount)
{
    int b = blockIdx.x;
    int t = threadIdx.x;
    int wave = t >> 6, lane = t & 63;   // 16 waves
    __shared__ float vals[Ss];
    __shared__ float sv[16];
    __shared__ int   si[16];
    __shared__ float thr_s;
    __shared__ int   cnt_s;

    vals[t]        = imp[b * Ss + t];
    vals[t + 1024] = imp[b * Ss + t + 1024];
    __syncthreads();

    for (int it = 0; it < Kk; ++it) {
        float v0 = vals[t], v1 = vals[t + 1024];
        float best = v0; int bidx = t;
        if (v1 > best) { best = v1; bidx = t + 1024; }
        #pragma unroll
        for (int off = 32; off > 0; off >>= 1) {
            float ov = __shfl_xor(best, off, 64);
            int   oi = __shfl_xor(bidx, off, 64);
            if (ov > best || (ov == best && oi < bidx)) { best = ov; bidx = oi; }
        }
        if (lane == 0) { sv[wave] = best; si[wave] = bidx; }
        __syncthreads();
        if (t == 0) {
            float bv = sv[0]; int br = si[0];
            #pragma unroll
            for (int w = 1; w < 16; ++w)
                if (sv[w] > bv || (sv[w] == bv && si[w] < br)) { bv = sv[w]; br = si[w]; }
            cand_idx[b * 64 + it] = br;
            vals[br] = -1e30f;
            if (it == Kk - 1) { thr_s = bv - DELTA; cnt_s = Kk; }
        }
        __syncthreads();
    }

    float thr = thr_s;
    if (vals[t] > thr) {
        int p = atomicAdd(&cnt_s, 1);
        if (p < 64) cand_idx[b * 64 + p] = t;
    }
    if (vals[t + 1024] > thr) {
        int p = atomicAdd(&cnt_s, 1);
        if (p < 64) cand_idx[b * 64 + p] = t + 1024;
    }
    __syncthreads();
    if (t == 0) ccount[b] = min(cnt_s, 64);
}

// ---------------------------------------------------------------------------
// Exact f32 rescore, phase 1: partial h for candidate rows, K split into 16
// chunks of 64 (grid 64 x 16 x Bb). relu deferred; atomic reorder ~1e-6.
// ---------------------------------------------------------------------------
__global__ void __launch_bounds__(256) rescore_h(
    const float* __restrict__ x, const float* __restrict__ Ws1,
    const int* __restrict__ cand_idx, const int* __restrict__ ccount,
    float* __restrict__ hbuf)
{
    const int c = blockIdx.x, kc = blockIdx.y, b = blockIdx.z;
    if (c >= ccount[b]) return;
    const int row = cand_idx[b * 64 + c];
    const int t = threadIdx.x;
    const int k0 = kc * 64;

    __shared__ float xs[64];
    if (t < 16)
        ((float4*)xs)[t] = ((const float4*)(x + ((size_t)(b * Ss + row)) * Dd + k0))[t];
    __syncthreads();

    float a0 = 0.f, a1 = 0.f;
    const float* W = Ws1 + (size_t)k0 * 512;
    #pragma unroll 16
    for (int kk = 0; kk < 64; ++kk) {
        float xv = xs[kk];
        a0 = fmaf(xv, W[kk * 512 + t], a0);
        a1 = fmaf(xv, W[kk * 512 + t + 256], a1);
    }
    float* hb = hbuf + ((size_t)(b * 64 + c)) * 512;
    atomicAdd(hb + t, a0);
    atomicAdd(hb + t + 256, a1);
}

// ---------------------------------------------------------------------------
// Rescore phase 2 (PARALLEL over candidates — one block each):
// z = sum relu(h + bs1) * Ws2 (pre-sigmoid; monotone => reference ranking).
// ---------------------------------------------------------------------------
__global__ void __launch_bounds__(256) rescore_fin(
    const float* __restrict__ hbuf, const float* __restrict__ bs1,
    const float* __restrict__ Ws2, const int* __restrict__ ccount,
    float* __restrict__ candz)
{
    const int c = blockIdx.x, b = blockIdx.y;
    if (c >= ccount[b]) return;
    const int t = threadIdx.x;
    __shared__ float red[256];
    const float* hb = hbuf + ((size_t)(b * 64 + c)) * 512;
    float zp = fmaxf(hb[t] + bs1[t], 0.f) * Ws2[t]
             + fmaxf(hb[t + 256] + bs1[t + 256], 0.f) * Ws2[t + 256];
    red[t] = zp;
    __syncthreads();
    for (int off = 128; off > 0; off >>= 1) {
        if (t < off) red[t] += red[t + off];
        __syncthreads();
    }
    if (t == 0) candz[b * 64 + c] = red[0];
}

// ---------------------------------------------------------------------------
// Final selection: exact top-16 among candidates (tie -> smaller row index).
// ---------------------------------------------------------------------------
__global__ void __launch_bounds__(64) select_k(
    const float* __restrict__ candz, const int* __restrict__ cand_idx,
    const int* __restrict__ ccount, int* __restrict__ sel_idx)
{
    const int b = blockIdx.x, t = threadIdx.x;
    const int cnt = ccount[b];
    float val = (t < cnt) ? candz[b * 64 + t] : -1e30f;
    int   row = (t < cnt) ? cand_idx[b * 64 + t] : 0x7fffffff;

    for (int it = 0; it < Kk; ++it) {
        float bv = val; int br = row;
        #pragma unroll
        for (int off = 1; off < 64; off <<= 1) {
            float ov = __shfl_xor(bv, off, 64);
            int   orw = __shfl_xor(br, off, 64);
            if (ov > bv || (ov == bv && orw < br)) { bv = ov; br = orw; }
        }
        if (row == br) val = -1e30f;
        if (t == 0) sel_idx[b * Kk + it] = br;
    }
}

// ---------------------------------------------------------------------------
// Sparse attention: ALL rows attend over the 16 selected keys (selected rows
// overwritten by the dense pipeline). One block per (b, h, 16 queries).
// ---------------------------------------------------------------------------
__global__ void __launch_bounds__(256) attn_sparse(
    const __bf16* __restrict__ q, const __bf16* __restrict__ k,
    const __bf16* __restrict__ v, const int* __restrict__ sel_idx,
    __bf16* __restrict__ att)
{
    const int b  = blockIdx.z;
    const int h  = blockIdx.y;
    const int q0 = blockIdx.x * 16;
    const int t  = threadIdx.x;

    __shared__ float KT[64][17];
    __shared__ float Vs[16][64];
    __shared__ float qsh[16][65];
    __shared__ float wsh[16][16];
    __shared__ int   sj[16];

    if (t < 16) sj[t] = sel_idx[b * Kk + t];
    __syncthreads();

    {
        int row = t >> 4, d0 = (t & 15) * 4;
        bf16x4 kv = *(const bf16x4*)(k + ((size_t)(b * Ss + sj[row])) * Dd + h * 64 + d0);
        bf16x4 vv = *(const bf16x4*)(v + ((size_t)(b * Ss + sj[row])) * Dd + h * 64 + d0);
        bf16x4 qv = *(const bf16x4*)(q + ((size_t)(b * Ss + q0 + row)) * Dd + h * 64 + d0);
        #pragma unroll
        for (int i = 0; i < 4; ++i) {
            KT[d0 + i][row]  = (float)kv[i];
            Vs[row][d0 + i]  = (float)vv[i];
            qsh[row][d0 + i] = (float)qv[i];
        }
    }
    __syncthreads();

    const int wave = t >> 6, lane = t & 63;
    const int ql = lane >> 4, j = lane & 15;
    const int qi = wave * 4 + ql;

    float s = 0.f;
    #pragma unroll
    for (int d = 0; d < 64; ++d) s = fmaf(qsh[qi][d], KT[d][j], s);
    s *= 0.125f;

    float m = s;
    #pragma unroll
    for (int off = 8; off > 0; off >>= 1) m = fmaxf(m, __shfl_xor(m, off, 16));
    float e = __expf(s - m);
    float sum = e;
    #pragma unroll
    for (int off = 8; off > 0; off >>= 1) sum += __shfl_xor(sum, off, 16);
    wsh[qi][j] = e / sum;

    #pragma unroll
    for (int q2 = 0; q2 < 4; ++q2) {
        int qq = wave * 4 + q2;
        float o = 0.f;
        #pragma unroll
        for (int jj = 0; jj < 16; ++jj)
            o = fmaf(wsh[qq][jj], Vs[jj][lane], o);
        att[((size_t)(b * Ss + q0 + qq)) * Dd + h * 64 + lane] = (__bf16)o;
    }
}

// ---------------------------------------------------------------------------
// Merged dense attention v2: 64-key chunks (grid 32 x Hh x Bb = 1024 blocks,
// ~4/CU all-resident), float4 LDS reads in the score phase. No max
// subtraction (|s| <= ~3 analytically; softmax shift-invariant, validated
// R9/R10). K-tile LDS reused for V after barrier.
// ---------------------------------------------------------------------------
__global__ void __launch_bounds__(256) attn_dense_one(
    const __bf16* __restrict__ q, const __bf16* __restrict__ k,
    const __bf16* __restrict__ v, const int* __restrict__ sel_idx,
    float* __restrict__ lsum, float* __restrict__ oacc)
{
    const int b  = blockIdx.z, h = blockIdx.y, j0 = blockIdx.x * 64;
    const int t  = threadIdx.x;

    __shared__ float Ks[64][68];     // 68: float4-aligned rows, odd/17 bank spread
    __shared__ float Qs[16][68];
    __shared__ float Es[16][80];

    #pragma unroll
    for (int l = 0; l < 2; ++l) {    // K chunk: 64 rows x 8 segs = 512
        int c = t + 256 * l;
        int row = c >> 3, seg = c & 7;
        bf16x8 kv = *(const bf16x8*)(k + ((size_t)(b * Ss + j0 + row)) * Dd + h * 64 + seg * 8);
        #pragma unroll
        for (int e = 0; e < 8; ++e) Ks[row][seg * 8 + e] = (float)kv[e];
    }
    if (t < 128) {                   // Q: 16 rows x 8 segs
        int row = t >> 3, seg = t & 7;
        int i = sel_idx[b * Kk + row];
        bf16x8 qv = *(const bf16x8*)(q + ((size_t)(b * Ss + i)) * Dd + h * 64 + seg * 8);
        #pragma unroll
        for (int e = 0; e < 8; ++e) Qs[row][seg * 8 + e] = (float)qv[e];
    }
    __syncthreads();

    const int qi = t >> 4, ks = t & 15;
    const int bhq = (b * Hh + h) * Kk + qi;
    float psum = 0.f;
    #pragma unroll
    for (int s8 = 0; s8 < 4; ++s8) {
        int j = ks + s8 * 16;
        float sdot = 0.f;
        #pragma unroll
        for (int d4 = 0; d4 < 16; ++d4) {
            float4 qv = *(const float4*)&Qs[qi][d4 * 4];
            float4 kv = *(const float4*)&Ks[j][d4 * 4];
            sdot += qv.x * kv.x + qv.y * kv.y + qv.z * kv.z + qv.w * kv.w;
        }
        float e = __expf(sdot * 0.125f);
        Es[qi][j] = e;
        psum += e;
    }
    #pragma unroll
    for (int off = 8; off > 0; off >>= 1) psum += __shfl_xor(psum, off, 16);
    if (ks == 0) atomicAdd(lsum + bhq, psum);
    __syncthreads();   // Es complete; Ks reads done -> overwrite with V

    #pragma unroll
    for (int l = 0; l < 2; ++l) {
        int c = t + 256 * l;
        int row = c >> 3, seg = c & 7;
        bf16x8 vv = *(const bf16x8*)(v + ((size_t)(b * Ss + j0 + row)) * Dd + h * 64 + seg * 8);
        #pragma unroll
        for (int e = 0; e < 8; ++e) Ks[row][seg * 8 + e] = (float)vv[e];
    }
    __syncthreads();

    const int d = t & 63, qg = t >> 6;
    #pragma unroll
    for (int qq = 0; qq < 4; ++qq) {
        int qx = qg * 4 + qq;
        float o = 0.f;
        #pragma unroll 8
        for (int jj = 0; jj < 64; ++jj)
            o = fmaf(Es[qx][jj], Ks[jj][d], o);
        atomicAdd(oacc + (size_t)((b * Hh + h) * Kk + qx) * 64 + d, o);
    }
}

// ---------------------------------------------------------------------------
// Dense attention finalize: att[selected rows] = oacc / lsum.
// ---------------------------------------------------------------------------
__global__ void __launch_bounds__(64) attn_dense_fin(
    const float* __restrict__ oacc, const float* __restrict__ lsum,
    const int* __restrict__ sel_idx, __bf16* __restrict__ att)
{
    int bid = blockIdx.x;
    int qi = bid & 15, h = (bid >> 4) & 15, b = bid >> 8;
    int bhq = (b * Hh + h) * Kk + qi;
    int i = sel_idx[b * Kk + qi];
    float val = oacc[(size_t)bhq * 64 + threadIdx.x] / lsum[bhq];
    att[((size_t)(b * Ss + i)) * Dd + h * 64 + threadIdx.x] = (__bf16)val;
}

// ---------------------------------------------------------------------------
extern "C" void kernel_launch(void* const* d_in, const int* in_sizes, int n_in,
                              void* d_out, int out_size, void* d_ws, size_t ws_size,
                              hipStream_t stream)
{
    const float* x   = (const float*)d_in[0];
    const float* Wq  = (const float*)d_in[1];
    const float* bq  = (const float*)d_in[2];
    const float* Wk  = (const float*)d_in[3];
    const float* bk  = (const float*)d_in[4];
    const float* Wv  = (const float*)d_in[5];
    const float* bv  = (const float*)d_in[6];
    const float* Wo  = (const float*)d_in[7];
    const float* bo  = (const float*)d_in[8];
    const float* Ws1 = (const float*)d_in[9];
    const float* bs1 = (const float*)d_in[10];
    const float* Ws2 = (const float*)d_in[11];
    float* out = (float*)d_out;

    const size_t MSD = (size_t)Bb * Ss * Dd;   // 4,194,304
    const int M = Bb * Ss;                     // 4096

    char* p = (char*)d_ws;
    __bf16* qb  = (__bf16*)p; p += MSD * sizeof(__bf16);
    __bf16* kb  = (__bf16*)p; p += MSD * sizeof(__bf16);
    __bf16* vb  = (__bf16*)p; p += MSD * sizeof(__bf16);
    __bf16* att = (__bf16*)p; p += MSD * sizeof(__bf16);
    __bf16* xb  = (__bf16*)p; p += MSD * sizeof(__bf16);
    __bf16* WqkvT = (__bf16*)p; p += (size_t)3 * Dd * Dd * sizeof(__bf16);
    __bf16* WoT   = (__bf16*)p; p += (size_t)Dd * Dd * sizeof(__bf16);
    __bf16* W1Th  = (__bf16*)p; p += (size_t)512 * Dd * sizeof(__bf16);
    float* imp  = (float*)p; p += (size_t)Bb * Ss * sizeof(float);
    int* sel_idx = (int*)p; p += (size_t)Bb * Kk * sizeof(int);
    float* oacc = (float*)p; p += (size_t)Bb * Hh * Kk * 64 * sizeof(float);
    float* lsum = (float*)p; p += (size_t)Bb * Hh * Kk * sizeof(float);
    float* hbuf = (float*)p; p += (size_t)Bb * 64 * 512 * sizeof(float);
    int* ccount   = (int*)p; p += Bb * sizeof(int);
    int* cand_idx = (int*)p; p += (size_t)Bb * 64 * sizeof(int);
    float* candz  = (float*)p; p += (size_t)Bb * 64 * sizeof(float);

    // 1) Merged prep: pack x -> bf16 (+ zero accumulators), weight transposes.
    prep_kernel<<<dim3(4096 + 5120), 256, 0, stream>>>(
        x, xb, imp, oacc, lsum, hbuf, ccount,
        Wq, Wk, Wv, Wo, WqkvT, WoT, Ws1, W1Th);
    // 2) FUSED: QKV projections + approximate indexer (256x128 tiles).
    gemm_qkv_ind<<<dim3(448), 512, 0, stream>>>(
        xb, WqkvT, W1Th, bq, bk, bv, qb, kb, vb, bs1, Ws2, imp);
    // 3) Candidate generation (approx top-16 + threshold band).
    topk_cand<<<dim3(Bb), 1024, 0, stream>>>(imp, cand_idx, ccount);
    // 4) Exact f32 rescore: parallel partial-h, parallel finalize, tiny select.
    rescore_h<<<dim3(64, 16, Bb), 256, 0, stream>>>(x, Ws1, cand_idx, ccount, hbuf);
    rescore_fin<<<dim3(64, Bb), 256, 0, stream>>>(hbuf, bs1, Ws2, ccount, candz);
    select_k<<<dim3(Bb), 64, 0, stream>>>(candz, cand_idx, ccount, sel_idx);
    // 5) Attention: sparse writes all rows; dense (64-key chunks) overwrites
    //    the 16 selected rows.
    attn_sparse<<<dim3(Ss / 16, Hh, Bb), 256, 0, stream>>>(qb, kb, vb, sel_idx, att);
    attn_dense_one<<<dim3(Ss / 64, Hh, Bb), 256, 0, stream>>>(qb, kb, vb, sel_idx, lsum, oacc);
    attn_dense_fin<<<dim3(Bb * Hh * Kk), 64, 0, stream>>>(oacc, lsum, sel_idx, att);
    // 6) Output projection: 64x128 tile, BK=64, 512 blocks.
    gemm_out<<<dim3(8, 64), 256, 0, stream>>>(att, WoT, bo, out, M, Dd, Dd);
}

// Round 12
// 243.006 us; speedup vs baseline: 1.1956x; 1.0394x over previous
//
#include <hip/hip_runtime.h>
#include <math.h>

// Problem constants
constexpr int Bb = 2, Ss = 2048, Dd = 1024, Hh = 16, Kk = 16;
constexpr float DELTA = 0.02f;   // candidate margin (~30 sigma of bf16 approx error)

typedef __bf16 bf16x8 __attribute__((ext_vector_type(8)));
typedef __bf16 bf16x4 __attribute__((ext_vector_type(4)));
typedef float  f32x4  __attribute__((ext_vector_type(4)));

__device__ __forceinline__ void gld_lds16(const void* g, void* l) {
    __builtin_amdgcn_global_load_lds(
        (const __attribute__((address_space(1))) unsigned int*)g,
        (__attribute__((address_space(3))) unsigned int*)l, 16, 0, 0);
}

// ---------------------------------------------------------------------------
// FUSED GEMM dispatch: uniform bf16 MFMA GEMM, 256x128 tile, BK=64 (16
// barrier-iters), 512 threads / 8 waves. cb 0..23 QKV (bias + bf16 store);
// cb 24..27 approximate indexer (relu*Ws2 row-reduce -> atomicAdd imp;
// exact rescore of a candidate band follows, so approx is selection-safe).
// XOR swizzle (seg ^ row&7) REQUIRED at BK=64: linear layout would be
// 16-way bank-conflicted (row stride 128 B); swizzled is 2-way (free).
// Grid 448 = 16 row-tiles x 28.
// ---------------------------------------------------------------------------
__global__ void __launch_bounds__(512) gemm_qkv_ind(
    const __bf16* __restrict__ xb, const __bf16* __restrict__ WqkvT,
    const __bf16* __restrict__ W1Th,
    const float* __restrict__ bq, const float* __restrict__ bk,
    const float* __restrict__ bv,
    __bf16* __restrict__ qb, __bf16* __restrict__ kb, __bf16* __restrict__ vb,
    const float* __restrict__ bs1, const float* __restrict__ Ws2,
    float* __restrict__ imp)
{
    __shared__ __bf16 As[256 * 64];   // 32 KB
    __shared__ __bf16 Bs[128 * 64];   // 16 KB

    const int bid  = blockIdx.x;
    const int cb   = bid % 28;
    const int bm   = (bid / 28) * 256;
    const int t    = threadIdx.x;
    const int wave = t >> 6;
    const int lane = t & 63;
    const int fr   = lane & 15;
    const int fq   = lane >> 4;
    const int K    = Dd;
    const bool ind = (cb >= 24);

    const __bf16* BT = ind ? (W1Th + (size_t)(cb - 24) * 128 * 1024)
                           : (WqkvT + (size_t)cb * 128 * 1024);

    const int wm = (wave & 3) * 64;
    const int wn = (wave >> 2) * 64;

    f32x4 acc[4][4] = {};

    for (int k0 = 0; k0 < K; k0 += 64) {
        // A: 256 rows x 64 k = 2048 chunks of 16 B; 4 per thread.
        #pragma unroll
        for (int l = 0; l < 4; ++l) {
            int c = l * 512 + t;
            int row = c >> 3, seg = (c & 7) ^ (row & 7);
            gld_lds16(xb + (size_t)(bm + row) * K + k0 + seg * 8,
                      As + (size_t)(l * 512 + wave * 64) * 8);
        }
        // B: 128 rows x 64 k = 1024 chunks; 2 per thread.
        #pragma unroll
        for (int l = 0; l < 2; ++l) {
            int c = l * 512 + t;
            int row = c >> 3, seg = (c & 7) ^ (row & 7);
            gld_lds16(BT + (size_t)row * K + k0 + seg * 8,
                      Bs + (size_t)(l * 512 + wave * 64) * 8);
        }
        __syncthreads();

        #pragma unroll
        for (int s = 0; s < 2; ++s) {
            bf16x8 af[4], bf[4];
            #pragma unroll
            for (int i = 0; i < 4; ++i) {
                int row = wm + i * 16 + fr;
                af[i] = *(const bf16x8*)(As + row * 64 + (((s * 4 + fq) ^ (row & 7)) * 8));
            }
            #pragma unroll
            for (int j = 0; j < 4; ++j) {
                int row = wn + j * 16 + fr;
                bf[j] = *(const bf16x8*)(Bs + row * 64 + (((s * 4 + fq) ^ (row & 7)) * 8));
            }
            #pragma unroll
            for (int i = 0; i < 4; ++i)
                #pragma unroll
                for (int j = 0; j < 4; ++j)
                    acc[i][j] = __builtin_amdgcn_mfma_f32_16x16x32_bf16(af[i], bf[j], acc[i][j], 0, 0, 0);
        }
        __syncthreads();
    }

    const int cr = (lane >> 4) * 4;
    const int cc = lane & 15;

    if (!ind) {
        const int zone = cb >> 3;                       // 0=q 1=k 2=v
        const int cl0  = cb * 128 - zone * 1024;
        const float* bias = (zone == 0) ? bq : (zone == 1) ? bk : bv;
        __bf16*      C    = (zone == 0) ? qb : (zone == 1) ? kb : vb;
        #pragma unroll
        for (int j = 0; j < 4; ++j) {
            int col = cl0 + wn + j * 16 + cc;
            float bb = bias[col];
            #pragma unroll
            for (int i = 0; i < 4; ++i) {
                #pragma unroll
                for (int r = 0; r < 4; ++r)
                    C[(size_t)(bm + wm + i * 16 + cr + r) * Dd + col] =
                        (__bf16)(acc[i][j][r] + bb);
            }
        }
    } else {
        const int hc0 = (cb - 24) * 128;
        float bb[4], w2[4];
        #pragma unroll
        for (int j = 0; j < 4; ++j) {
            int col = hc0 + wn + j * 16 + cc;
            bb[j] = bs1[col];
            w2[j] = Ws2[col];
        }
        #pragma unroll
        for (int i = 0; i < 4; ++i) {
            #pragma unroll
            for (int r = 0; r < 4; ++r) {
                float vsum = 0.f;
                #pragma unroll
                for (int j = 0; j < 4; ++j)
                    vsum += fmaxf(acc[i][j][r] + bb[j], 0.f) * w2[j];
                #pragma unroll
                for (int off = 8; off > 0; off >>= 1)
                    vsum += __shfl_xor(vsum, off, 16);
                if (cc == 0)
                    atomicAdd(imp + (bm + wm + i * 16 + cr + r), vsum);
            }
        }
    }
}

// ---------------------------------------------------------------------------
// Out-projection GEMM: out = att @ WoT^T + bo, f32 out. 64x128 tile, BK=64.
// ---------------------------------------------------------------------------
__global__ void __launch_bounds__(256) gemm_out(
    const __bf16* __restrict__ A, const __bf16* __restrict__ BT,
    const float* __restrict__ bias, float* __restrict__ C, int M, int N, int K)
{
    __shared__ __bf16 As[64 * 64];
    __shared__ __bf16 Bs[128 * 64];

    const int t    = threadIdx.x;
    const int wave = t >> 6;
    const int lane = t & 63;
    const int bm   = blockIdx.y * 64;
    const int bn   = blockIdx.x * 128;
    const int wm   = (wave & 1) * 32;
    const int wn   = (wave >> 1) * 64;
    const int fr   = lane & 15;
    const int fq   = lane >> 4;

    f32x4 acc[2][4] = {};

    for (int k0 = 0; k0 < K; k0 += 64) {
        #pragma unroll
        for (int l = 0; l < 2; ++l) {
            int c = l * 256 + t;
            int row = c >> 3, seg = (c & 7) ^ (row & 7);
            gld_lds16(A + (size_t)(bm + row) * K + k0 + seg * 8,
                      As + (size_t)(l * 256 + wave * 64) * 8);
        }
        #pragma unroll
        for (int l = 0; l < 4; ++l) {
            int c = l * 256 + t;
            int row = c >> 3, seg = (c & 7) ^ (row & 7);
            gld_lds16(BT + (size_t)(bn + row) * K + k0 + seg * 8,
                      Bs + (size_t)(l * 256 + wave * 64) * 8);
        }
        __syncthreads();

        #pragma unroll
        for (int s = 0; s < 2; ++s) {
            bf16x8 af[2], bf[4];
            #pragma unroll
            for (int i = 0; i < 2; ++i) {
                int row = wm + i * 16 + fr;
                af[i] = *(const bf16x8*)(As + row * 64 + (((s * 4 + fq) ^ (row & 7)) * 8));
            }
            #pragma unroll
            for (int j = 0; j < 4; ++j) {
                int row = wn + j * 16 + fr;
                bf[j] = *(const bf16x8*)(Bs + row * 64 + (((s * 4 + fq) ^ (row & 7)) * 8));
            }
            #pragma unroll
            for (int i = 0; i < 2; ++i)
                #pragma unroll
                for (int j = 0; j < 4; ++j)
                    acc[i][j] = __builtin_amdgcn_mfma_f32_16x16x32_bf16(af[i], bf[j], acc[i][j], 0, 0, 0);
        }
        __syncthreads();
    }

    const int cr = (lane >> 4) * 4;
    const int cc = lane & 15;
    #pragma unroll
    for (int j = 0; j < 4; ++j) {
        int col = bn + wn + j * 16 + cc;
        float bb = bias[col];
        #pragma unroll
        for (int i = 0; i < 2; ++i) {
            #pragma unroll
            for (int r = 0; r < 4; ++r)
                C[(size_t)(bm + wm + i * 16 + cr + r) * N + col] = acc[i][j][r] + bb;
        }
    }
}

// ---------------------------------------------------------------------------
// Merged prep: bid<4096 -> pack x (f32 -> bf16) + zero-init accumulators;
// bid>=4096 -> weight transpose+pack.
// ---------------------------------------------------------------------------
__global__ void __launch_bounds__(256) prep_kernel(
    const float* __restrict__ x, __bf16* __restrict__ xb,
    float* __restrict__ imp, float* __restrict__ oacc,
    float* __restrict__ lsum, float* __restrict__ hbuf,
    int* __restrict__ ccount,
    const float* __restrict__ W0, const float* __restrict__ W1,
    const float* __restrict__ W2, const float* __restrict__ W3,
    __bf16* __restrict__ WqkvT, __bf16* __restrict__ WoT,
    const float* __restrict__ Ws1, __bf16* __restrict__ Th)
{
    __shared__ float tile[32][33];
    const int bid = blockIdx.x;

    if (bid < 4096) {
        int i = bid * 256 + threadIdx.x;
        if (i < Bb * Ss) imp[i] = 0.f;
        if (i < Bb * Hh * Kk * 64) oacc[i] = 0.f;
        if (i < Bb * Hh * Kk) lsum[i] = 0.f;
        if (i < Bb * 64 * 512) hbuf[i] = 0.f;
        if (i < Bb) ccount[i] = 0;
        float4 v = ((const float4*)x)[i];
        bf16x4 h = { (__bf16)v.x, (__bf16)v.y, (__bf16)v.z, (__bf16)v.w };
        ((bf16x4*)xb)[i] = h;
        return;
    }

    int tid = bid - 4096;
    int z   = tid >> 10;
    int rem = tid & 1023;
    int n0  = (rem & 31) * 32;
    int k0  = (rem >> 5) * 32;
    int tx = threadIdx.x & 31, ty = threadIdx.x >> 5;

    if (z < 4) {
        const float* W = (z == 0) ? W0 : (z == 1) ? W1 : (z == 2) ? W2 : W3;
        __bf16*      T = (z < 3) ? (WqkvT + (size_t)z * 1024 * 1024) : WoT;
        #pragma unroll
        for (int i = 0; i < 32; i += 8)
            tile[ty + i][tx] = W[(size_t)(k0 + ty + i) * 1024 + n0 + tx];
        __syncthreads();
        #pragma unroll
        for (int i = 0; i < 32; i += 8)
            T[(size_t)(n0 + ty + i) * 1024 + k0 + tx] = (__bf16)tile[tx][ty + i];
    } else {
        if (n0 >= 512) return;
        #pragma unroll
        for (int i = 0; i < 32; i += 8)
            tile[ty + i][tx] = Ws1[(size_t)(k0 + ty + i) * 512 + n0 + tx];
        __syncthreads();
        #pragma unroll
        for (int i = 0; i < 32; i += 8)
            Th[(size_t)(n0 + ty + i) * 1024 + k0 + tx] = (__bf16)tile[tx][ty + i];
    }
}

// ---------------------------------------------------------------------------
// Candidate generation on approx imp: 16 argmax passes at 1024 threads
// + threshold band z16_approx - DELTA. Cap 64.
// ---------------------------------------------------------------------------
__global__ void __launch_bounds__(1024) topk_cand(
    const float* __restrict__ imp, int* __restrict__ cand_idx,
    int* __restrict__ ccount)
{
    int b = blockIdx.x;
    int t = threadIdx.x;
    int wave = t >> 6, lane = t & 63;   // 16 waves
    __shared__ float vals[Ss];
    __shared__ float sv[16];
    __shared__ int   si[16];
    __shared__ float thr_s;
    __shared__ int   cnt_s;

    vals[t]        = imp[b * Ss + t];
    vals[t + 1024] = imp[b * Ss + t + 1024];
    __syncthreads();

    for (int it = 0; it < Kk; ++it) {
        float v0 = vals[t], v1 = vals[t + 1024];
        float best = v0; int bidx = t;
        if (v1 > best) { best = v1; bidx = t + 1024; }
        #pragma unroll
        for (int off = 32; off > 0; off >>= 1) {
            float ov = __shfl_xor(best, off, 64);
            int   oi = __shfl_xor(bidx, off, 64);
            if (ov > best || (ov == best && oi < bidx)) { best = ov; bidx = oi; }
        }
        if (lane == 0) { sv[wave] = best; si[wave] = bidx; }
        __syncthreads();
        if (t == 0) {
            float bv = sv[0]; int br = si[0];
            #pragma unroll
            for (int w = 1; w < 16; ++w)
                if (sv[w] > bv || (sv[w] == bv && si[w] < br)) { bv = sv[w]; br = si[w]; }
            cand_idx[b * 64 + it] = br;
            vals[br] = -1e30f;
            if (it == Kk - 1) { thr_s = bv - DELTA; cnt_s = Kk; }
        }
        __syncthreads();
    }

    float thr = thr_s;
    if (vals[t] > thr) {
        int p = atomicAdd(&cnt_s, 1);
        if (p < 64) cand_idx[b * 64 + p] = t;
    }
    if (vals[t + 1024] > thr) {
        int p = atomicAdd(&cnt_s, 1);
        if (p < 64) cand_idx[b * 64 + p] = t + 1024;
    }
    __syncthreads();
    if (t == 0) ccount[b] = min(cnt_s, 64);
}

// ---------------------------------------------------------------------------
// Exact f32 rescore, phase 1: partial h for candidate rows, K split into 16
// chunks of 64 (grid 64 x 16 x Bb). relu deferred; atomic reorder ~1e-6.
// ---------------------------------------------------------------------------
__global__ void __launch_bounds__(256) rescore_h(
    const float* __restrict__ x, const float* __restrict__ Ws1,
    const int* __restrict__ cand_idx, const int* __restrict__ ccount,
    float* __restrict__ hbuf)
{
    const int c = blockIdx.x, kc = blockIdx.y, b = blockIdx.z;
    if (c >= ccount[b]) return;
    const int row = cand_idx[b * 64 + c];
    const int t = threadIdx.x;
    const int k0 = kc * 64;

    __shared__ float xs[64];
    if (t < 16)
        ((float4*)xs)[t] = ((const float4*)(x + ((size_t)(b * Ss + row)) * Dd + k0))[t];
    __syncthreads();

    float a0 = 0.f, a1 = 0.f;
    const float* W = Ws1 + (size_t)k0 * 512;
    #pragma unroll 16
    for (int kk = 0; kk < 64; ++kk) {
        float xv = xs[kk];
        a0 = fmaf(xv, W[kk * 512 + t], a0);
        a1 = fmaf(xv, W[kk * 512 + t + 256], a1);
    }
    float* hb = hbuf + ((size_t)(b * 64 + c)) * 512;
    atomicAdd(hb + t, a0);
    atomicAdd(hb + t + 256, a1);
}

// ---------------------------------------------------------------------------
// Rescore phase 2 (parallel over candidates): z = sum relu(h+bs1)*Ws2.
// ---------------------------------------------------------------------------
__global__ void __launch_bounds__(256) rescore_fin(
    const float* __restrict__ hbuf, const float* __restrict__ bs1,
    const float* __restrict__ Ws2, const int* __restrict__ ccount,
    float* __restrict__ candz)
{
    const int c = blockIdx.x, b = blockIdx.y;
    if (c >= ccount[b]) return;
    const int t = threadIdx.x;
    __shared__ float red[256];
    const float* hb = hbuf + ((size_t)(b * 64 + c)) * 512;
    float zp = fmaxf(hb[t] + bs1[t], 0.f) * Ws2[t]
             + fmaxf(hb[t + 256] + bs1[t + 256], 0.f) * Ws2[t + 256];
    red[t] = zp;
    __syncthreads();
    for (int off = 128; off > 0; off >>= 1) {
        if (t < off) red[t] += red[t + off];
        __syncthreads();
    }
    if (t == 0) candz[b * 64 + c] = red[0];
}

// ---------------------------------------------------------------------------
// Final selection: exact top-16 among candidates (tie -> smaller row index).
// ---------------------------------------------------------------------------
__global__ void __launch_bounds__(64) select_k(
    const float* __restrict__ candz, const int* __restrict__ cand_idx,
    const int* __restrict__ ccount, int* __restrict__ sel_idx)
{
    const int b = blockIdx.x, t = threadIdx.x;
    const int cnt = ccount[b];
    float val = (t < cnt) ? candz[b * 64 + t] : -1e30f;
    int   row = (t < cnt) ? cand_idx[b * 64 + t] : 0x7fffffff;

    for (int it = 0; it < Kk; ++it) {
        float bv = val; int br = row;
        #pragma unroll
        for (int off = 1; off < 64; off <<= 1) {
            float ov = __shfl_xor(bv, off, 64);
            int   orw = __shfl_xor(br, off, 64);
            if (ov > bv || (ov == bv && orw < br)) { bv = ov; br = orw; }
        }
        if (row == br) val = -1e30f;
        if (t == 0) sel_idx[b * Kk + it] = br;
    }
}

// ---------------------------------------------------------------------------
// FUSED attention dispatch: blockIdx.x < 128 -> sparse path (all rows over
// the 16 selected keys; selected rows overwritten later); else -> dense path
// (16 selected queries x 64-key chunk -> exp/lsum/PV atomics). Independent
// workloads co-scheduled in one dispatch. Manual LDS union (26.9 KB).
// Grid (160, Hh, Bb).
// ---------------------------------------------------------------------------
__global__ void __launch_bounds__(256) attn_all(
    const __bf16* __restrict__ q, const __bf16* __restrict__ k,
    const __bf16* __restrict__ v, const int* __restrict__ sel_idx,
    __bf16* __restrict__ att, float* __restrict__ lsum,
    float* __restrict__ oacc)
{
    __shared__ __align__(16) float sm[6720];   // 26.9 KB union
    const int b = blockIdx.z, h = blockIdx.y;
    const int t = threadIdx.x;

    if (blockIdx.x < 128) {
        // ---------------- sparse path ----------------
        float (*KT)[17]  = (float(*)[17])sm;            // 64x17
        float (*Vs)[64]  = (float(*)[64])(sm + 1088);   // 16x64
        float (*qsh)[65] = (float(*)[65])(sm + 2112);   // 16x65
        float (*wsh)[16] = (float(*)[16])(sm + 3152);   // 16x16
        int*  sj         = (int*)(sm + 3408);
        const int q0 = blockIdx.x * 16;

        if (t < 16) sj[t] = sel_idx[b * Kk + t];
        __syncthreads();

        {
            int row = t >> 4, d0 = (t & 15) * 4;
            bf16x4 kv = *(const bf16x4*)(k + ((size_t)(b * Ss + sj[row])) * Dd + h * 64 + d0);
            bf16x4 vv = *(const bf16x4*)(v + ((size_t)(b * Ss + sj[row])) * Dd + h * 64 + d0);
            bf16x4 qv = *(const bf16x4*)(q + ((size_t)(b * Ss + q0 + row)) * Dd + h * 64 + d0);
            #pragma unroll
            for (int i = 0; i < 4; ++i) {
                KT[d0 + i][row]  = (float)kv[i];
                Vs[row][d0 + i]  = (float)vv[i];
                qsh[row][d0 + i] = (float)qv[i];
            }
        }
        __syncthreads();

        const int wave = t >> 6, lane = t & 63;
        const int ql = lane >> 4, j = lane & 15;
        const int qi = wave * 4 + ql;

        float s = 0.f;
        #pragma unroll
        for (int d = 0; d < 64; ++d) s = fmaf(qsh[qi][d], KT[d][j], s);
        s *= 0.125f;

        float m = s;
        #pragma unroll
        for (int off = 8; off > 0; off >>= 1) m = fmaxf(m, __shfl_xor(m, off, 16));
        float e = __expf(s - m);
        float sum = e;
        #pragma unroll
        for (int off = 8; off > 0; off >>= 1) sum += __shfl_xor(sum, off, 16);
        wsh[qi][j] = e / sum;   // read back only within this wave

        #pragma unroll
        for (int q2 = 0; q2 < 4; ++q2) {
            int qq = wave * 4 + q2;
            float o = 0.f;
            #pragma unroll
            for (int jj = 0; jj < 16; ++jj)
                o = fmaf(wsh[qq][jj], Vs[jj][lane], o);
            att[((size_t)(b * Ss + q0 + qq)) * Dd + h * 64 + lane] = (__bf16)o;
        }
    } else {
        // ---------------- dense path (64-key chunk) ----------------
        float (*Ks)[68] = (float(*)[68])sm;             // 64x68 (reused for V)
        float (*Qs)[68] = (float(*)[68])(sm + 4352);    // 16x68
        float (*Es)[80] = (float(*)[80])(sm + 5440);    // 16x80
        const int j0 = (blockIdx.x - 128) * 64;

        #pragma unroll
        for (int l = 0; l < 2; ++l) {
            int c = t + 256 * l;
            int row = c >> 3, seg = c & 7;
            bf16x8 kv = *(const bf16x8*)(k + ((size_t)(b * Ss + j0 + row)) * Dd + h * 64 + seg * 8);
            #pragma unroll
            for (int e = 0; e < 8; ++e) Ks[row][seg * 8 + e] = (float)kv[e];
        }
        if (t < 128) {
            int row = t >> 3, seg = t & 7;
            int i = sel_idx[b * Kk + row];
            bf16x8 qv = *(const bf16x8*)(q + ((size_t)(b * Ss + i)) * Dd + h * 64 + seg * 8);
            #pragma unroll
            for (int e = 0; e < 8; ++e) Qs[row][seg * 8 + e] = (float)qv[e];
        }
        __syncthreads();

        const int qi = t >> 4, ks = t & 15;
        const int bhq = (b * Hh + h) * Kk + qi;
        float psum = 0.f;
        #pragma unroll
        for (int s8 = 0; s8 < 4; ++s8) {
            int j = ks + s8 * 16;
            float sdot = 0.f;
            #pragma unroll
            for (int d4 = 0; d4 < 16; ++d4) {
                float4 qv = *(const float4*)&Qs[qi][d4 * 4];
                float4 kv = *(const float4*)&Ks[j][d4 * 4];
                sdot += qv.x * kv.x + qv.y * kv.y + qv.z * kv.z + qv.w * kv.w;
            }
            float e = __expf(sdot * 0.125f);   // no max-sub: |s|<=~3, shift-inv
            Es[qi][j] = e;
            psum += e;
        }
        #pragma unroll
        for (int off = 8; off > 0; off >>= 1) psum += __shfl_xor(psum, off, 16);
        if (ks == 0) atomicAdd(lsum + bhq, psum);
        __syncthreads();   // Es complete; Ks reads done -> overwrite with V

        #pragma unroll
        for (int l = 0; l < 2; ++l) {
            int c = t + 256 * l;
            int row = c >> 3, seg = c & 7;
            bf16x8 vv = *(const bf16x8*)(v + ((size_t)(b * Ss + j0 + row)) * Dd + h * 64 + seg * 8);
            #pragma unroll
            for (int e = 0; e < 8; ++e) Ks[row][seg * 8 + e] = (float)vv[e];
        }
        __syncthreads();

        const int d = t & 63, qg = t >> 6;
        #pragma unroll
        for (int qq = 0; qq < 4; ++qq) {
            int qx = qg * 4 + qq;
            float o = 0.f;
            #pragma unroll 8
            for (int jj = 0; jj < 64; ++jj)
                o = fmaf(Es[qx][jj], Ks[jj][d], o);
            atomicAdd(oacc + (size_t)((b * Hh + h) * Kk + qx) * 64 + d, o);
        }
    }
}

// ---------------------------------------------------------------------------
// Dense attention finalize: att[selected rows] = oacc / lsum.
// ---------------------------------------------------------------------------
__global__ void __launch_bounds__(64) attn_dense_fin(
    const float* __restrict__ oacc, const float* __restrict__ lsum,
    const int* __restrict__ sel_idx, __bf16* __restrict__ att)
{
    int bid = blockIdx.x;
    int qi = bid & 15, h = (bid >> 4) & 15, b = bid >> 8;
    int bhq = (b * Hh + h) * Kk + qi;
    int i = sel_idx[b * Kk + qi];
    float val = oacc[(size_t)bhq * 64 + threadIdx.x] / lsum[bhq];
    att[((size_t)(b * Ss + i)) * Dd + h * 64 + threadIdx.x] = (__bf16)val;
}

// ---------------------------------------------------------------------------
extern "C" void kernel_launch(void* const* d_in, const int* in_sizes, int n_in,
                              void* d_out, int out_size, void* d_ws, size_t ws_size,
                              hipStream_t stream)
{
    const float* x   = (const float*)d_in[0];
    const float* Wq  = (const float*)d_in[1];
    const float* bq  = (const float*)d_in[2];
    const float* Wk  = (const float*)d_in[3];
    const float* bk  = (const float*)d_in[4];
    const float* Wv  = (const float*)d_in[5];
    const float* bv  = (const float*)d_in[6];
    const float* Wo  = (const float*)d_in[7];
    const float* bo  = (const float*)d_in[8];
    const float* Ws1 = (const float*)d_in[9];
    const float* bs1 = (const float*)d_in[10];
    const float* Ws2 = (const float*)d_in[11];
    float* out = (float*)d_out;

    const size_t MSD = (size_t)Bb * Ss * Dd;   // 4,194,304
    const int M = Bb * Ss;                     // 4096

    char* p = (char*)d_ws;
    __bf16* qb  = (__bf16*)p; p += MSD * sizeof(__bf16);
    __bf16* kb  = (__bf16*)p; p += MSD * sizeof(__bf16);
    __bf16* vb  = (__bf16*)p; p += MSD * sizeof(__bf16);
    __bf16* att = (__bf16*)p; p += MSD * sizeof(__bf16);
    __bf16* xb  = (__bf16*)p; p += MSD * sizeof(__bf16);
    __bf16* WqkvT = (__bf16*)p; p += (size_t)3 * Dd * Dd * sizeof(__bf16);
    __bf16* WoT   = (__bf16*)p; p += (size_t)Dd * Dd * sizeof(__bf16);
    __bf16* W1Th  = (__bf16*)p; p += (size_t)512 * Dd * sizeof(__bf16);
    float* imp  = (float*)p; p += (size_t)Bb * Ss * sizeof(float);
    int* sel_idx = (int*)p; p += (size_t)Bb * Kk * sizeof(int);
    float* oacc = (float*)p; p += (size_t)Bb * Hh * Kk * 64 * sizeof(float);
    float* lsum = (float*)p; p += (size_t)Bb * Hh * Kk * sizeof(float);
    float* hbuf = (float*)p; p += (size_t)Bb * 64 * 512 * sizeof(float);
    int* ccount   = (int*)p; p += Bb * sizeof(int);
    int* cand_idx = (int*)p; p += (size_t)Bb * 64 * sizeof(int);
    float* candz  = (float*)p; p += (size_t)Bb * 64 * sizeof(float);

    // 1) Merged prep: pack x -> bf16 (+ zero accumulators), weight transposes.
    prep_kernel<<<dim3(4096 + 5120), 256, 0, stream>>>(
        x, xb, imp, oacc, lsum, hbuf, ccount,
        Wq, Wk, Wv, Wo, WqkvT, WoT, Ws1, W1Th);
    // 2) FUSED: QKV projections + approximate indexer (256x128, BK=64).
    gemm_qkv_ind<<<dim3(448), 512, 0, stream>>>(
        xb, WqkvT, W1Th, bq, bk, bv, qb, kb, vb, bs1, Ws2, imp);
    // 3) Candidate generation (approx top-16 + threshold band).
    topk_cand<<<dim3(Bb), 1024, 0, stream>>>(imp, cand_idx, ccount);
    // 4) Exact f32 rescore: parallel partial-h, parallel finalize, tiny select.
    rescore_h<<<dim3(64, 16, Bb), 256, 0, stream>>>(x, Ws1, cand_idx, ccount, hbuf);
    rescore_fin<<<dim3(64, Bb), 256, 0, stream>>>(hbuf, bs1, Ws2, ccount, candz);
    select_k<<<dim3(Bb), 64, 0, stream>>>(candz, cand_idx, ccount, sel_idx);
    // 5) FUSED attention: sparse (x<128) + dense 64-key chunks (x>=128).
    attn_all<<<dim3(160, Hh, Bb), 256, 0, stream>>>(
        qb, kb, vb, sel_idx, att, lsum, oacc);
    attn_dense_fin<<<dim3(Bb * Hh * Kk), 64, 0, stream>>>(oacc, lsum, sel_idx, att);
    // 6) Output projection: 64x128 tile, BK=64, 512 blocks.
    gemm_out<<<dim3(8, 64), 256, 0, stream>>>(att, WoT, bo, out, M, Dd, Dd);
}